// Round 2
// baseline (12294.556 us; speedup 1.0000x reference)
//
#include <hip/hip_runtime.h>
#include <stdint.h>
#include <math.h>

#define NB 512
#define NS 200
#define NH 128
#define NH3 384

// ---------------- workspace layout (float offsets) ----------------
constexpr int O_H0   = 0;                 // 512*128 h ping
constexpr int O_H1   = O_H0 + NB*NH;      // 512*128 h pong
constexpr int O_XP   = O_H1 + NB*NH;      // 512*2   last_out
constexpr int O_HT   = O_XP + NB*2;       // 512*128 Hterm = Wa_h @ h_new
constexpr int O_AS0  = O_HT + NB*NH;      // 128 each: attention folded vectors
constexpr int O_AS1  = O_AS0 + NH;
constexpr int O_AD0  = O_AS1 + NH;
constexpr int O_AD1  = O_AD0 + NH;
constexpr int O_AC   = O_AD1 + NH;
constexpr int O_DS0  = O_AC + NH;         // decoder-head folded vectors
constexpr int O_DS1  = O_DS0 + NH;
constexpr int O_DC   = O_DS1 + NH;
constexpr int O_C0   = O_DC + NH;         // Wd_ctx folded vectors
constexpr int O_C1   = O_C0 + NH;
constexpr int O_CB   = O_C1 + NH;
constexpr int O_KEYS = O_CB + NH;         // 400 uint32 (200 step keys, interleaved (k0,k1))
constexpr int WS_FLOATS = O_KEYS + 2*NS;

// ---------------- XLA-exact scalar helpers ----------------
// XLA llvm_ir::EmitFastTanh: clamp +-9, |x|<0.0004 -> x, rational P/Q,
// Horner WITHOUT fma (XLA emits plain fmul/fadd, no contraction).
__device__ __forceinline__ float xla_tanhf(float x) {
  float cx = fminf(fmaxf(x, -9.0f), 9.0f);
  float x2 = __fmul_rn(cx, cx);
  float p = -2.76076847742355e-16f;
  p = __fadd_rn(__fmul_rn(x2, p), 2.00018790482477e-13f);
  p = __fadd_rn(__fmul_rn(x2, p), -8.60467152213735e-11f);
  p = __fadd_rn(__fmul_rn(x2, p), 5.12229709037114e-08f);
  p = __fadd_rn(__fmul_rn(x2, p), 1.48572235717979e-05f);
  p = __fadd_rn(__fmul_rn(x2, p), 6.37261928875436e-04f);
  p = __fadd_rn(__fmul_rn(x2, p), 4.89352455891786e-03f);
  p = __fmul_rn(cx, p);
  float q = 1.19825839466702e-06f;
  q = __fadd_rn(__fmul_rn(x2, q), 1.18534705686654e-04f);
  q = __fadd_rn(__fmul_rn(x2, q), 2.26843463243900e-03f);
  q = __fadd_rn(__fmul_rn(x2, q), 4.89352518554385e-03f);
  float r = __fdiv_rn(p, q);
  return (fabsf(x) < 0.0004f) ? x : r;
}

// XLA LogisticExpander: logistic(x) = 0.5 + 0.5*tanh(0.5*x)
__device__ __forceinline__ float xla_sigmoidf(float x) {
  return __fadd_rn(0.5f, __fmul_rn(0.5f, xla_tanhf(__fmul_rn(0.5f, x))));
}

// Threefry-2x32, 20 rounds (JAX semantics)
__device__ __forceinline__ uint32_t rotl32(uint32_t v, int r) {
  return (v << r) | (v >> (32 - r));
}
__device__ __forceinline__ void threefry2x32(uint32_t k0, uint32_t k1,
                                             uint32_t x0, uint32_t x1,
                                             uint32_t& o0, uint32_t& o1) {
  uint32_t k2 = k0 ^ k1 ^ 0x1BD11BDAu;
  x0 += k0; x1 += k1;
  #define TFR(r) { x0 += x1; x1 = rotl32(x1, r); x1 ^= x0; }
  TFR(13) TFR(15) TFR(26) TFR(6)
  x0 += k1; x1 += k2 + 1u;
  TFR(17) TFR(29) TFR(16) TFR(24)
  x0 += k2; x1 += k0 + 2u;
  TFR(13) TFR(15) TFR(26) TFR(6)
  x0 += k0; x1 += k1 + 3u;
  TFR(17) TFR(29) TFR(16) TFR(24)
  x0 += k1; x1 += k2 + 4u;
  TFR(13) TFR(15) TFR(26) TFR(6)
  x0 += k2; x1 += k0 + 5u;
  #undef TFR
  o0 = x0; o1 = x1;
}

// JAX uniform(tiny,1) -> gumbel, bit-exact construction
__device__ __forceinline__ float bits_to_gumbel(uint32_t bits) {
  const float kTiny = 1.1754943508222875e-38f;
  float f = __fsub_rn(__uint_as_float((bits >> 9) | 0x3F800000u), 1.0f);
  float u = __fadd_rn(__fmul_rn(f, __fsub_rn(1.0f, kTiny)), kTiny);
  u = fmaxf(kTiny, u);
  return -logf(-logf(u));
}

// ---------------- precompute: folded vectors + step keys ----------------
__global__ void k_pre(const float* __restrict__ sW, const float* __restrict__ sb,
                      const float* __restrict__ dW, const float* __restrict__ db,
                      const float* __restrict__ Wa, const float* __restrict__ Wd,
                      float* __restrict__ wsf) {
  int t = threadIdx.x;
  if (t < NH) {
    int h = t;
    const float* war = Wa + (size_t)h * NH3;
    float as0 = 0.f, as1 = 0.f, ad0 = 0.f, ad1 = 0.f, ac = 0.f;
    for (int k = 0; k < NH; ++k) {
      as0 = fmaf(war[k],     sW[k*2+0], as0);
      as1 = fmaf(war[k],     sW[k*2+1], as1);
      ad0 = fmaf(war[NH+k],  dW[k*2+0], ad0);
      ad1 = fmaf(war[NH+k],  dW[k*2+1], ad1);
      ac  = fmaf(war[k],     sb[k],     ac);
    }
    for (int k = 0; k < NH; ++k) ac = fmaf(war[NH+k], db[k], ac);
    wsf[O_AS0+h] = as0; wsf[O_AS1+h] = as1;
    wsf[O_AD0+h] = ad0; wsf[O_AD1+h] = ad1; wsf[O_AC+h] = ac;

    const float* wdr = Wd + (size_t)h * 256;
    float ds0 = 0.f, ds1 = 0.f, dc = 0.f, c0 = 0.f, c1 = 0.f, cb = 0.f;
    for (int k = 0; k < NH; ++k) {
      ds0 = fmaf(wdr[k],    sW[k*2+0], ds0);
      ds1 = fmaf(wdr[k],    sW[k*2+1], ds1);
      dc  = fmaf(wdr[k],    sb[k],     dc);
      c0  = fmaf(wdr[NH+k], sW[k*2+0], c0);
      c1  = fmaf(wdr[NH+k], sW[k*2+1], c1);
      cb  = fmaf(wdr[NH+k], sb[k],     cb);
    }
    wsf[O_DS0+h] = ds0; wsf[O_DS1+h] = ds1; wsf[O_DC+h] = dc;
    wsf[O_C0+h]  = c0;  wsf[O_C1+h]  = c1;  wsf[O_CB+h] = cb;
  }
  if (t < NS) {
    // jax_threefry_partitionable=True (default since JAX 0.5.0):
    // split(key(42), 200) is fold-like: key_i = threefry((0,42), (0, i)),
    // new key = BOTH output words stacked.
    uint32_t w0, w1;
    threefry2x32(0u, 42u, 0u, (uint32_t)t, w0, w1);
    uint32_t* kf = (uint32_t*)(wsf + O_KEYS);
    kf[2*t] = w0; kf[2*t + 1] = w1;
  }
}

// ---------------- init: h = h0 broadcast, x_prev = x0 broadcast ----------------
__global__ void k_init(const float* __restrict__ x0, const float* __restrict__ h0,
                       float* __restrict__ wsf) {
  int i = blockIdx.x * blockDim.x + threadIdx.x; // 65536 threads
  wsf[O_H0 + i] = h0[i & 127];
  if (i < NB * 2) wsf[O_XP + i] = x0[i & 1];
}

// ---------------- GRU + Hterm (faithful sequential-k FMA) ----------------
#define BR 4
__global__ __launch_bounds__(256) void k_gru(
    const float* __restrict__ Wemb, const float* __restrict__ bemb,
    const float* __restrict__ Wih,  const float* __restrict__ Whh,
    const float* __restrict__ bih,  const float* __restrict__ bhh,
    const float* __restrict__ Wa,
    const float* __restrict__ h_in, float* __restrict__ h_out,
    float* __restrict__ wsf) {
  __shared__ float h_l[BR][132], emb_l[BR][132], hn_l[BR][132];
  __shared__ float gi_l[BR][388], gh_l[BR][388];
  __shared__ float xp[BR][2];
  int t = threadIdx.x;
  int b0 = blockIdx.x * BR;

  for (int i = t; i < BR*NH; i += 256) {
    int b = i >> 7, hh = i & 127;
    h_l[b][hh] = h_in[(size_t)(b0 + b)*NH + hh];
  }
  if (t < BR*2) xp[t >> 1][t & 1] = wsf[O_XP + b0*2 + t];
  __syncthreads();

  // emb = x @ Wemb^T + bemb   (K=2, fma chain then bias add)
  for (int i = t; i < BR*NH; i += 256) {
    int b = i >> 7, hh = i & 127;
    float e = fmaf(xp[b][1], Wemb[hh*2+1], __fmul_rn(xp[b][0], Wemb[hh*2+0]));
    emb_l[b][hh] = __fadd_rn(e, bemb[hh]);
  }
  __syncthreads();

  // gi = emb @ Wih^T + bih ;  gh = h @ Whh^T + bhh  (sequential k, single acc)
  {
    int bl = t & 3, jl = t >> 2;
    for (int jj = 0; jj < NH3; jj += 64) {
      int j = jl + jj;
      const float4* wi = (const float4*)(Wih + (size_t)j*NH);
      const float4* wh = (const float4*)(Whh + (size_t)j*NH);
      float acci = 0.f, acch = 0.f;
      for (int k4 = 0; k4 < 32; ++k4) {
        float4 a = wi[k4], c = wh[k4];
        int k = k4 * 4;
        acci = fmaf(a.x, emb_l[bl][k],   acci);
        acci = fmaf(a.y, emb_l[bl][k+1], acci);
        acci = fmaf(a.z, emb_l[bl][k+2], acci);
        acci = fmaf(a.w, emb_l[bl][k+3], acci);
        acch = fmaf(c.x, h_l[bl][k],   acch);
        acch = fmaf(c.y, h_l[bl][k+1], acch);
        acch = fmaf(c.z, h_l[bl][k+2], acch);
        acch = fmaf(c.w, h_l[bl][k+3], acch);
      }
      gi_l[bl][j] = __fadd_rn(acci, bih[j]);
      gh_l[bl][j] = __fadd_rn(acch, bhh[j]);
    }
  }
  __syncthreads();

  // gates (torch order r,z,n) and h_new = (1-z)*n + z*h
  for (int i = t; i < BR*NH; i += 256) {
    int b = i >> 7, hh = i & 127;
    float r = xla_sigmoidf(__fadd_rn(gi_l[b][hh],        gh_l[b][hh]));
    float z = xla_sigmoidf(__fadd_rn(gi_l[b][hh+NH],     gh_l[b][hh+NH]));
    float n = xla_tanhf(__fadd_rn(gi_l[b][hh+2*NH], __fmul_rn(r, gh_l[b][hh+2*NH])));
    float hv = h_l[b][hh];
    float hn = __fadd_rn(__fmul_rn(__fsub_rn(1.0f, z), n), __fmul_rn(z, hv));
    hn_l[b][hh] = hn;
    h_out[(size_t)(b0 + b)*NH + hh] = hn;
  }
  __syncthreads();

  // Hterm = Wa[:,256:384] @ h_new   (sequential k)
  for (int i = t; i < BR*NH; i += 256) {
    int b = i >> 7, hh = i & 127;
    const float4* war = (const float4*)(Wa + (size_t)hh*NH3 + 2*NH);
    float acc = 0.f;
    for (int k4 = 0; k4 < 32; ++k4) {
      float4 a = war[k4];
      int k = k4 * 4;
      acc = fmaf(a.x, hn_l[b][k],   acc);
      acc = fmaf(a.y, hn_l[b][k+1], acc);
      acc = fmaf(a.z, hn_l[b][k+2], acc);
      acc = fmaf(a.w, hn_l[b][k+3], acc);
    }
    wsf[O_HT + (size_t)(b0 + b)*NH + hh] = acc;
  }
}

// ---------------- per-batch-row step: attention, decode, sample ----------------
__global__ __launch_bounds__(256) void k_step(
    const float* __restrict__ stat, const float* __restrict__ dyn,
    const float* __restrict__ va,   const float* __restrict__ vd,
    float* __restrict__ wsf, float* __restrict__ out, int step) {
  __shared__ float st0[NS], st1[NS], dy0[NS], dy1[NS];
  __shared__ float Ht[NH], As0[NH], As1[NH], Ad0[NH], Ad1[NH], Ac[NH];
  __shared__ float Ds0[NH], Ds1[NH], Dc[NH], Cw0[NH], Cw1[NH], Cwb[NH];
  __shared__ float va_l[NH], vd_l[NH], Ct[NH];
  __shared__ float sc[NS], ex[NS], at[NS];
  __shared__ float red[256];
  __shared__ int ri[256];
  __shared__ float Rv[4];

  int t = threadIdx.x;
  int b = blockIdx.x;

  if (t < NS) {
    st0[t] = stat[(size_t)b*2*NS + t];
    st1[t] = stat[(size_t)b*2*NS + NS + t];
    dy0[t] = dyn[(size_t)b*2*NS + t];
    dy1[t] = dyn[(size_t)b*2*NS + NS + t];
  }
  if (t < NH) {
    Ht[t]  = wsf[O_HT + (size_t)b*NH + t];
    As0[t] = wsf[O_AS0+t]; As1[t] = wsf[O_AS1+t];
    Ad0[t] = wsf[O_AD0+t]; Ad1[t] = wsf[O_AD1+t]; Ac[t] = wsf[O_AC+t];
    Ds0[t] = wsf[O_DS0+t]; Ds1[t] = wsf[O_DS1+t]; Dc[t] = wsf[O_DC+t];
    Cw0[t] = wsf[O_C0+t];  Cw1[t] = wsf[O_C1+t];  Cwb[t] = wsf[O_CB+t];
    va_l[t] = va[t]; vd_l[t] = vd[t];
  }
  __syncthreads();

  // attention scores: va . tanh(Wa @ [s_enc; d_enc; h_new])
  if (t < NS) {
    float s0 = st0[t], s1 = st1[t], d0 = dy0[t], d1 = dy1[t];
    float acc = 0.f;
    for (int h = 0; h < NH; ++h) {
      float e = fmaf(As1[h], s1, __fmul_rn(As0[h], s0));
      e = fmaf(Ad0[h], d0, e);
      e = fmaf(Ad1[h], d1, e);
      e = __fadd_rn(e, Ac[h]);
      e = __fadd_rn(e, Ht[h]);
      acc = fmaf(va_l[h], xla_tanhf(e), acc);
    }
    sc[t] = acc;
  }
  __syncthreads();

  // softmax over s (attention)
  red[t] = (t < NS) ? sc[t] : -INFINITY; __syncthreads();
  for (int o = 128; o > 0; o >>= 1) { if (t < o) red[t] = fmaxf(red[t], red[t+o]); __syncthreads(); }
  float m = red[0]; __syncthreads();
  if (t < NS) ex[t] = expf(__fsub_rn(sc[t], m));
  __syncthreads();
  red[t] = (t < NS) ? ex[t] : 0.f; __syncthreads();
  for (int o = 128; o > 0; o >>= 1) { if (t < o) red[t] = __fadd_rn(red[t], red[t+o]); __syncthreads(); }
  float sume = red[0]; __syncthreads();
  if (t < NS) at[t] = __fdiv_rn(ex[t], sume);
  __syncthreads();

  // R0 = sum attn*st0 ; R1 = sum attn*st1 ; Rsum = sum attn
  red[t] = (t < NS) ? __fmul_rn(at[t], st0[t]) : 0.f; __syncthreads();
  for (int o = 128; o > 0; o >>= 1) { if (t < o) red[t] = __fadd_rn(red[t], red[t+o]); __syncthreads(); }
  if (t == 0) Rv[0] = red[0]; __syncthreads();
  red[t] = (t < NS) ? __fmul_rn(at[t], st1[t]) : 0.f; __syncthreads();
  for (int o = 128; o > 0; o >>= 1) { if (t < o) red[t] = __fadd_rn(red[t], red[t+o]); __syncthreads(); }
  if (t == 0) Rv[1] = red[0]; __syncthreads();
  red[t] = (t < NS) ? at[t] : 0.f; __syncthreads();
  for (int o = 128; o > 0; o >>= 1) { if (t < o) red[t] = __fadd_rn(red[t], red[t+o]); __syncthreads(); }
  if (t == 0) Rv[2] = red[0]; __syncthreads();

  // Cterm = Wd[:,128:256] @ context (context is rank-2 in attn-weighted inputs)
  if (t < NH)
    Ct[t] = fmaf(Rv[0], Cw0[t], fmaf(Rv[1], Cw1[t], __fmul_rn(Rv[2], Cwb[t])));
  __syncthreads();

  // decoder logits: vd . tanh(Wd @ [s_enc; context])
  if (t < NS) {
    float s0 = st0[t], s1 = st1[t];
    float acc = 0.f;
    for (int h = 0; h < NH; ++h) {
      float d = fmaf(Ds1[h], s1, __fmul_rn(Ds0[h], s0));
      d = __fadd_rn(d, Dc[h]);
      d = __fadd_rn(d, Ct[h]);
      acc = fmaf(vd_l[h], xla_tanhf(d), acc);
    }
    sc[t] = acc;
  }
  __syncthreads();

  // probs softmax
  red[t] = (t < NS) ? sc[t] : -INFINITY; __syncthreads();
  for (int o = 128; o > 0; o >>= 1) { if (t < o) red[t] = fmaxf(red[t], red[t+o]); __syncthreads(); }
  float m2 = red[0]; __syncthreads();
  if (t < NS) ex[t] = expf(__fsub_rn(sc[t], m2));
  __syncthreads();
  red[t] = (t < NS) ? ex[t] : 0.f; __syncthreads();
  for (int o = 128; o > 0; o >>= 1) { if (t < o) red[t] = __fadd_rn(red[t], red[t+o]); __syncthreads(); }
  float sume2 = red[0]; __syncthreads();

  // gumbel-max sampling: partitionable random_bits = o0 ^ o1 of
  // threefry(step_key, (0, linear_index)), linear_index = b*NS + s
  const uint32_t* kf = (const uint32_t*)(wsf + O_KEYS);
  uint32_t k0 = kf[2*step], k1 = kf[2*step + 1];
  float gv = -INFINITY;
  if (t < NS) {
    uint32_t j = (uint32_t)(b*NS + t);
    uint32_t w0, w1;
    threefry2x32(k0, k1, 0u, j, w0, w1);
    uint32_t bits = w0 ^ w1;
    gv = __fadd_rn(bits_to_gumbel(bits), sc[t]);
  }
  red[t] = gv; ri[t] = t; __syncthreads();
  for (int o = 128; o > 0; o >>= 1) {
    if (t < o) {
      float v2 = red[t+o]; int i2 = ri[t+o];
      if (v2 > red[t] || (v2 == red[t] && i2 < ri[t])) { red[t] = v2; ri[t] = i2; }
    }
    __syncthreads();
  }
  if (t == 0) {
    int widx = ri[0];
    out[(size_t)b*NS + step] = (float)widx;                        // idx_seq.T
    out[(size_t)NB*NS + (size_t)b*NS + step] = __fdiv_rn(ex[widx], sume2); // prob_seq.T
    wsf[O_XP + b*2 + 0] = st0[widx];   // next_out = static[b,:,idx]
    wsf[O_XP + b*2 + 1] = st1[widx];
  }
}

// ---------------- host launch ----------------
extern "C" void kernel_launch(void* const* d_in, const int* in_sizes, int n_in,
                              void* d_out, int out_size, void* d_ws, size_t ws_size,
                              hipStream_t stream) {
  (void)in_sizes; (void)n_in; (void)out_size;
  const float* stat = (const float*)d_in[0];
  const float* dyn  = (const float*)d_in[1];
  const float* sW   = (const float*)d_in[2];
  const float* sb   = (const float*)d_in[3];
  const float* dW   = (const float*)d_in[4];
  const float* db   = (const float*)d_in[5];
  const float* x0   = (const float*)d_in[6];
  const float* h0   = (const float*)d_in[7];
  const float* Wemb = (const float*)d_in[8];
  const float* bemb = (const float*)d_in[9];
  const float* Wih  = (const float*)d_in[10];
  const float* Whh  = (const float*)d_in[11];
  const float* bih  = (const float*)d_in[12];
  const float* bhh  = (const float*)d_in[13];
  const float* Wa   = (const float*)d_in[14];
  const float* va   = (const float*)d_in[15];
  const float* Wd   = (const float*)d_in[16];
  const float* vd   = (const float*)d_in[17];
  float* out = (float*)d_out;
  float* wsf = (float*)d_ws;

  if (ws_size < (size_t)WS_FLOATS * sizeof(float)) return;

  k_pre<<<1, 256, 0, stream>>>(sW, sb, dW, db, Wa, Wd, wsf);
  k_init<<<256, 256, 0, stream>>>(x0, h0, wsf);

  for (int step = 0; step < NS; ++step) {
    const float* hin = wsf + ((step & 1) ? O_H1 : O_H0);
    float* hout      = wsf + ((step & 1) ? O_H0 : O_H1);
    k_gru<<<NB/BR, 256, 0, stream>>>(Wemb, bemb, Wih, Whh, bih, bhh, Wa,
                                     hin, hout, wsf);
    k_step<<<NB, 256, 0, stream>>>(stat, dyn, va, vd, wsf, out, step);
  }
}